// Round 1
// baseline (218.674 us; speedup 1.0000x reference)
//
#include <hip/hip_runtime.h>
#include <math.h>

// Per-position head-vs-head attention. The reference's Hilbert gather +
// inverse scatter cancel exactly because the op is pointwise in the sequence
// dimension (scores are [B,S,h,h], softmax over the last h, PV within the
// same position). So: for each (b,s) and head group g in {0,1}:
//   S[i][j] = dot(q[i], k[j]) * 0.125   (i,j group-local, d=64)
//   attn = softmax_j(S);  out[i] = sum_j attn[i][j] * v[j]
//
// Memory-bound: 268 MB total traffic, ~0.54 GFLOP.

#define HEADS 16
#define DIM 64
#define ROWP 68              // LDS row stride in floats (+4 pad breaks stride-64 bank conflicts)
#define POS_PER_BLOCK 2

__global__ void hilbert_attn_kernel(const float* __restrict__ q,
                                    const float* __restrict__ k,
                                    const float* __restrict__ v,
                                    float* __restrict__ out,
                                    int npos)
{
    __shared__ float sq[POS_PER_BLOCK][HEADS][ROWP];
    __shared__ float sk[POS_PER_BLOCK][HEADS][ROWP];
    __shared__ float sv[POS_PER_BLOCK][HEADS][ROWP];

    const int t = threadIdx.x;
    const long long blockPos = (long long)blockIdx.x * POS_PER_BLOCK;

    // ---- Load: 2 positions x 1024 contiguous floats per tensor.
    // 256 threads x one float4 each per (tensor, position): fully coalesced.
    {
        const int fo  = t * 4;        // float offset within position [0,1024)
        const int row = fo >> 6;      // head row
        const int col = fo & 63;      // dim col (multiple of 4 -> float4 aligned, ROWP%4==0)
        for (int p = 0; p < POS_PER_BLOCK; ++p) {
            long long pos = blockPos + p;
            if (pos >= npos) break;
            const long long gbase = pos * (HEADS * DIM) + fo;
            float4 a = *(const float4*)(q + gbase);
            float4 b = *(const float4*)(k + gbase);
            float4 c = *(const float4*)(v + gbase);
            *(float4*)&sq[p][row][col] = a;
            *(float4*)&sk[p][row][col] = b;
            *(float4*)&sv[p][row][col] = c;
        }
    }
    __syncthreads();

    const int p    = t >> 7;      // position within block (0/1)
    const int tt   = t & 127;
    const int i    = tt >> 3;     // head 0..15
    const int j    = tt & 7;      // group-local column / dim-subchunk
    const int grp  = i >> 3;      // head group 0/1
    const int lane = t & 63;

    if (blockPos + p >= npos) return;

    // ---- Phase A: one score per thread: S[i][j] = dot64(q[i], k[grp*8+j]) * scale
    float acc = 0.f;
    const int krow = grp * 8 + j;
    #pragma unroll
    for (int d = 0; d < DIM; d += 4) {
        float4 a = *(const float4*)&sq[p][i][d];       // broadcast across j (free)
        float4 b = *(const float4*)&sk[p][krow][d];    // stride-68 rows: no conflict
        acc += a.x * b.x + a.y * b.y + a.z * b.z + a.w * b.w;
    }
    float s = acc * 0.125f;   // HEAD_DIM^-0.5

    // ---- Softmax over the 8 j-lanes (aligned 8-lane groups within the wave)
    float m = s;
    #pragma unroll
    for (int off = 1; off < 8; off <<= 1)
        m = fmaxf(m, __shfl_xor(m, off));
    float e = __expf(s - m);
    float sum = e;
    #pragma unroll
    for (int off = 1; off < 8; off <<= 1)
        sum += __shfl_xor(sum, off);
    const float attn = e / sum;

    // ---- Phase B: out[i][j*8 .. j*8+8) = sum_jj attn[i][jj] * v[grp*8+jj][j*8..+8)
    const int col = j * 8;
    float o0 = 0.f, o1 = 0.f, o2 = 0.f, o3 = 0.f;
    float o4 = 0.f, o5 = 0.f, o6 = 0.f, o7 = 0.f;
    const int vbase = grp * 8;
    #pragma unroll
    for (int jj = 0; jj < 8; ++jj) {
        float a = __shfl(attn, (lane & 56) | jj);      // attn[i][jj] from sibling lane
        const float4* vp = (const float4*)&sv[p][vbase + jj][col];  // broadcast/2-way: free
        float4 v0 = vp[0], v1 = vp[1];
        o0 += a * v0.x; o1 += a * v0.y; o2 += a * v0.z; o3 += a * v0.w;
        o4 += a * v1.x; o5 += a * v1.y; o6 += a * v1.z; o7 += a * v1.w;
    }

    // ---- Store: lane l writes 32B at offset l*8 floats -> contiguous, coalesced
    const long long gaddr = (blockPos + p) * (HEADS * DIM) + i * DIM + col;
    *(float4*)(out + gaddr)     = make_float4(o0, o1, o2, o3);
    *(float4*)(out + gaddr + 4) = make_float4(o4, o5, o6, o7);
}

extern "C" void kernel_launch(void* const* d_in, const int* in_sizes, int n_in,
                              void* d_out, int out_size, void* d_ws, size_t ws_size,
                              hipStream_t stream) {
    const float* q = (const float*)d_in[0];
    const float* k = (const float*)d_in[1];
    const float* v = (const float*)d_in[2];
    float* out = (float*)d_out;

    const int npos = in_sizes[0] / (HEADS * DIM);   // B*S = 16384
    const int blocks = (npos + POS_PER_BLOCK - 1) / POS_PER_BLOCK;
    hilbert_attn_kernel<<<blocks, 256, 0, stream>>>(q, k, v, out, npos);
}

// Round 2
// 210.377 us; speedup vs baseline: 1.0394x; 1.0394x over previous
//
#include <hip/hip_runtime.h>
#include <math.h>

// Per-position head-vs-head attention (Hilbert perm cancels; see R0 notes).
// R1 redesign: one WAVE per position, zero __syncthreads. Each wave stages
// only k,v into a private LDS slice; q sub-rows are lane-private (direct
// global reads); softmax is in-lane after a 2-step shfl_xor dot reduction.
// Rationale: R0 was latency/structure bound (88us @ 1.9 TB/s, VALU 12%) --
// the block barrier convoyed all 4 waves on the slowest load.

#define HEADS 16
#define DIM 64
// LDS per tensor slice: grp0 512 floats, +4 pad, grp1 512 floats.
// Pad makes per-instr address sets land 2-per-bank-span (free, m136).
#define GSTRIDE 516
#define TSLICE  (2 * GSTRIDE)      // 1032 floats per tensor (k or v)
#define WSLICE  (2 * TSLICE)       // 2064 floats per wave slice
#define WAVES_PER_BLOCK 4

__global__ void __launch_bounds__(256) hilbert_attn_kernel(
    const float* __restrict__ q,
    const float* __restrict__ k,
    const float* __restrict__ v,
    float* __restrict__ out,
    int npos)
{
    __shared__ float lds[WAVES_PER_BLOCK * WSLICE];   // 33,024 B

    const int t    = threadIdx.x;
    const int wave = t >> 6;
    const int lane = t & 63;
    const long long pos = (long long)blockIdx.x * WAVES_PER_BLOCK + wave;
    if (pos >= npos) return;          // wave-uniform; no barriers below

    float* kk = lds + wave * WSLICE;
    float* vv = kk + TSLICE;

    const long long gbase = pos * (HEADS * DIM);

    const int i   = lane >> 2;        // head 0..15
    const int s   = lane & 3;         // 16-float sub-chunk of dim
    const int grp = i >> 3;           // head group

    // ---- Issue q sub-row loads (lane-private, 16 floats) early.
    const float* qp = q + gbase + i * DIM + s * 16;
    float4 q0 = *(const float4*)(qp + 0);
    float4 q1 = *(const float4*)(qp + 4);
    float4 q2 = *(const float4*)(qp + 8);
    float4 q3 = *(const float4*)(qp + 12);

    // ---- Stage k,v into wave-private LDS (4KB each). 4 coalesced f4 loads
    // per tensor per lane; dest offset +4 floats for the 2nd group block.
    {
        #pragma unroll
        for (int it = 0; it < 4; ++it) {
            const int sfo = it * 256 + lane * 4;              // source float offset
            const int dfo = sfo + ((it >= 2) ? 4 : 0);        // +pad for grp1 rows
            float4 a = *(const float4*)(k + gbase + sfo);
            float4 b = *(const float4*)(v + gbase + sfo);
            *(float4*)(kk + dfo) = a;
            *(float4*)(vv + dfo) = b;
        }
    }
    // No barrier: LDS slice is wave-private; compiler inserts lgkm/vm waits.

    // ---- Phase A: partial scores over this lane's 16 dims, all 8 j.
    const float* kg = kk + grp * GSTRIDE;
    float sc[8];
    #pragma unroll
    for (int j = 0; j < 8; ++j) {
        const float* kr = kg + j * DIM + s * 16;
        float4 k0 = *(const float4*)(kr + 0);
        float4 k1 = *(const float4*)(kr + 4);
        float4 k2 = *(const float4*)(kr + 8);
        float4 k3 = *(const float4*)(kr + 12);
        float a = q0.x*k0.x + q0.y*k0.y + q0.z*k0.z + q0.w*k0.w
                + q1.x*k1.x + q1.y*k1.y + q1.z*k1.z + q1.w*k1.w
                + q2.x*k2.x + q2.y*k2.y + q2.z*k2.z + q2.w*k2.w
                + q3.x*k3.x + q3.y*k3.y + q3.z*k3.z + q3.w*k3.w;
        sc[j] = a;
    }
    // Complete dots across the 4 s-lanes (lanes i*4+s are contiguous).
    #pragma unroll
    for (int j = 0; j < 8; ++j) {
        sc[j] += __shfl_xor(sc[j], 1);
        sc[j] += __shfl_xor(sc[j], 2);
        sc[j] *= 0.125f;              // HEAD_DIM^-0.5
    }

    // ---- Softmax fully in-lane (every s-lane holds the full score row).
    float m = sc[0];
    #pragma unroll
    for (int j = 1; j < 8; ++j) m = fmaxf(m, sc[j]);
    float sum = 0.f;
    float at[8];
    #pragma unroll
    for (int j = 0; j < 8; ++j) { at[j] = __expf(sc[j] - m); sum += at[j]; }
    const float inv = 1.f / sum;
    #pragma unroll
    for (int j = 0; j < 8; ++j) at[j] *= inv;

    // ---- Phase B: out[i][s*16 .. s*16+16) = sum_j at[j] * v[g*8+j][chunk s]
    const float* vg = vv + grp * GSTRIDE;
    float4 o0 = make_float4(0,0,0,0), o1 = o0, o2 = o0, o3 = o0;
    #pragma unroll
    for (int j = 0; j < 8; ++j) {
        const float a = at[j];
        const float* vr = vg + j * DIM + s * 16;
        float4 v0 = *(const float4*)(vr + 0);
        float4 v1 = *(const float4*)(vr + 4);
        float4 v2 = *(const float4*)(vr + 8);
        float4 v3 = *(const float4*)(vr + 12);
        o0.x += a*v0.x; o0.y += a*v0.y; o0.z += a*v0.z; o0.w += a*v0.w;
        o1.x += a*v1.x; o1.y += a*v1.y; o1.z += a*v1.z; o1.w += a*v1.w;
        o2.x += a*v2.x; o2.y += a*v2.y; o2.z += a*v2.z; o2.w += a*v2.w;
        o3.x += a*v3.x; o3.y += a*v3.y; o3.z += a*v3.z; o3.w += a*v3.w;
    }

    // ---- Store lane-private 64B (L2 write-back merges neighbors into lines).
    float* op = out + gbase + i * DIM + s * 16;
    *(float4*)(op + 0)  = o0;
    *(float4*)(op + 4)  = o1;
    *(float4*)(op + 8)  = o2;
    *(float4*)(op + 12) = o3;
}

extern "C" void kernel_launch(void* const* d_in, const int* in_sizes, int n_in,
                              void* d_out, int out_size, void* d_ws, size_t ws_size,
                              hipStream_t stream) {
    const float* q = (const float*)d_in[0];
    const float* k = (const float*)d_in[1];
    const float* v = (const float*)d_in[2];
    float* out = (float*)d_out;

    const int npos = in_sizes[0] / (HEADS * DIM);   // B*S = 16384
    const int blocks = (npos + WAVES_PER_BLOCK - 1) / WAVES_PER_BLOCK;
    hilbert_attn_kernel<<<blocks, 256, 0, stream>>>(q, k, v, out, npos);
}